// Round 2
// baseline (7076.076 us; speedup 1.0000x reference)
//
#include <hip/hip_runtime.h>
#include <cstdint>
#include <cstddef>

typedef float    float4v __attribute__((ext_vector_type(4)));
typedef _Float16 f16x2   __attribute__((ext_vector_type(2)));
typedef _Float16 f16x8   __attribute__((ext_vector_type(8)));

#define DI __device__ __forceinline__

static const int Bsz = 64, Tlen = 2048, Hd = 128, G4 = 512;  // 4H=512
static const int Mrows = Bsz * Tlen;                          // 131072

DI float sigf_fast(float x) {
    float e = __builtin_amdgcn_exp2f(-1.442695041f * x);
    return __builtin_amdgcn_rcpf(1.f + e);
}
DI float tanhf_fast(float x) {
    float e = __builtin_amdgcn_exp2f(-2.885390082f * x);
    return 2.f * __builtin_amdgcn_rcpf(1.f + e) - 1.f;
}

#if defined(__has_builtin)
#if __has_builtin(__builtin_amdgcn_fdot2)
#define HAVE_FDOT2 1
#endif
#endif

DI float fdot2(f16x2 a, f16x2 b, float c) {
#ifdef HAVE_FDOT2
    return __builtin_amdgcn_fdot2(a, b, c, false);
#else
    return c + (float)a[0] * (float)b[0] + (float)a[1] * (float)b[1];
#endif
}

DI float dot8(f16x8 w, f16x8 h, float acc) {
    f16x2 w0 = __builtin_shufflevector(w, w, 0, 1), h0 = __builtin_shufflevector(h, h, 0, 1);
    f16x2 w1 = __builtin_shufflevector(w, w, 2, 3), h1 = __builtin_shufflevector(h, h, 2, 3);
    f16x2 w2 = __builtin_shufflevector(w, w, 4, 5), h2 = __builtin_shufflevector(h, h, 4, 5);
    f16x2 w3 = __builtin_shufflevector(w, w, 6, 7), h3 = __builtin_shufflevector(h, h, 6, 7);
    acc = fdot2(w0, h0, acc);
    acc = fdot2(w1, h1, acc);
    acc = fdot2(w2, h2, acc);
    acc = fdot2(w3, h3, acc);
    return acc;
}

// load 8 consecutive f32, convert to f16x8 (exact-ish: rel err 2^-11)
DI f16x8 cvt8(const float* p) {
    float4v u = *(const float4v*)p;
    float4v w = *(const float4v*)(p + 4);
    f16x8 o;
    o[0] = (_Float16)u[0]; o[1] = (_Float16)u[1]; o[2] = (_Float16)u[2]; o[3] = (_Float16)u[3];
    o[4] = (_Float16)w[0]; o[5] = (_Float16)w[1]; o[6] = (_Float16)w[2]; o[7] = (_Float16)w[3];
    return o;
}

// ---------------------------------------------------------------------------
// GEMM: C[M,N] = A[M,128] @ W[N,128]^T (+bias). f32 (or f16) A, f32 W,
// f16-convert fragments, MFMA f32_16x16x32_f16, f32 accumulate.
// Tile: 64(M) x 64(N) per WG of 256 threads (wave w owns M-subtile w).
// A-operand layout: lane holds A[m=lane&15][k=(lane>>4)*8+j], j=0..7. [guide §3]
// C/D layout: col=lane&15, row=(lane>>4)*4+reg. [m89]
// ---------------------------------------------------------------------------
template <bool A_F16, bool OUT_F32>
__global__ __launch_bounds__(256) void gemm_k128(
    const void* __restrict__ Av, const float* __restrict__ W,
    const float* __restrict__ bias, void* __restrict__ Cout, int M, int N)
{
    const int lane = threadIdx.x & 63, wave = threadIdx.x >> 6;
    const int m0 = blockIdx.x * 64 + wave * 16;
    const int n0 = blockIdx.y * 64;
    const int r15 = lane & 15, kg = lane >> 4;   // kg in 0..3

    f16x8 a[4];
    if (A_F16) {
        const f16x8* Ar = (const f16x8*)((const _Float16*)Av + (size_t)(m0 + r15) * 128);
#pragma unroll
        for (int kt = 0; kt < 4; kt++) a[kt] = Ar[kt * 4 + kg];
    } else {
        const float* Ar = (const float*)Av + (size_t)(m0 + r15) * 128;
#pragma unroll
        for (int kt = 0; kt < 4; kt++) a[kt] = cvt8(Ar + kt * 32 + kg * 8);
    }

    f16x8 bfrg[4][4];
#pragma unroll
    for (int nt = 0; nt < 4; nt++) {
        const float* Wr = W + (size_t)(n0 + nt * 16 + r15) * 128;
#pragma unroll
        for (int kt = 0; kt < 4; kt++) bfrg[nt][kt] = cvt8(Wr + kt * 32 + kg * 8);
    }

    float4v acc[4] = {};
#pragma unroll
    for (int kt = 0; kt < 4; kt++)
#pragma unroll
        for (int nt = 0; nt < 4; nt++)
            acc[nt] = __builtin_amdgcn_mfma_f32_16x16x32_f16(a[kt], bfrg[nt][kt], acc[nt], 0, 0, 0);

#pragma unroll
    for (int nt = 0; nt < 4; nt++) {
        int n = n0 + nt * 16 + r15;
        float bv = bias ? bias[n] : 0.f;
#pragma unroll
        for (int r = 0; r < 4; r++) {
            int m = m0 + kg * 4 + r;
            float v = acc[nt][r] + bv;
            if (OUT_F32) ((float*)Cout)[(size_t)m * N + n] = v;
            else         ((_Float16*)Cout)[(size_t)m * N + n] = (_Float16)v;
        }
    }
}

// ---------------------------------------------------------------------------
// LSTM recurrence, one layer. One WG per batch element (64 WGs x 512 threads).
// Thread g owns gate-row g: Whh[g,:] held in VGPRs as 64 f16 pairs.
// h broadcast via LDS (f16). gates = bval + xpart + Whh[g]·h -> activation
// -> LDS -> threads<128 update (c,h). 2 barriers/step, T=2048 steps.
// ---------------------------------------------------------------------------
template <bool HAS_XP, bool WRITE_Y, bool INIT>
__global__ __launch_bounds__(512, 2) void lstm_rec(
    const float* __restrict__ U,                     // Whh [512,128] f32
    const float* __restrict__ bi, const float* __restrict__ bh,
    const _Float16* __restrict__ XP,                 // [B,T,512] f16 or null
    const float* ih, const float* ic,                // init state [B,128] or null
    _Float16* __restrict__ Yout,                     // [B,T,128] f16 or null
    float* fh, float* fc, int T)
{
    const int b = blockIdx.x;
    const int g = threadIdx.x;                       // 0..511
    __shared__ alignas(16) _Float16 hs[128];
    __shared__ float as_[512];

    // Load Whh row g (f32) -> f16x8[16]
    f16x8 w8[16];
    {
        const float* ur = U + (size_t)g * 128;
#pragma unroll
        for (int i = 0; i < 16; i++) w8[i] = cvt8(ur + i * 8);
    }
    const float bval = bi[g] + bh[g];
    const int j = g & 127, q = g >> 7;               // q: 0=i 1=f 2=g 3=o

    float c = 0.f, hcur = 0.f;
    if (g < 128) {
        if (INIT) { c = ic[(size_t)b * 128 + g]; hcur = ih[(size_t)b * 128 + g]; }
        hs[g] = (_Float16)hcur;
    }
    const _Float16* xprow = HAS_XP ? (XP + (size_t)b * T * 512 + g) : (const _Float16*)nullptr;
    float xp = HAS_XP ? (float)xprow[0] : 0.f;
    __syncthreads();

    for (int t = 0; t < T; t++) {
        float xpn = 0.f;
        if (HAS_XP && (t + 1 < T)) xpn = (float)xprow[(size_t)(t + 1) * 512];  // prefetch

        const f16x8* hv8 = (const f16x8*)hs;
        float a0 = bval + xp, a1 = 0.f, a2 = 0.f, a3 = 0.f;
#pragma unroll
        for (int i = 0; i < 16; i += 4) {
            f16x8 h0 = hv8[i], h1 = hv8[i + 1], h2 = hv8[i + 2], h3 = hv8[i + 3];
            a0 = dot8(w8[i],     h0, a0);
            a1 = dot8(w8[i + 1], h1, a1);
            a2 = dot8(w8[i + 2], h2, a2);
            a3 = dot8(w8[i + 3], h3, a3);
        }
        float pre = (a0 + a1) + (a2 + a3);
        float act = (q == 2) ? tanhf_fast(pre) : sigf_fast(pre);
        as_[g] = act;
        __syncthreads();                              // acts ready; all dots done reading hs
        if (g < 128) {
            float iv = as_[j], fv = as_[128 + j], gv = as_[256 + j], ov = as_[384 + j];
            c = fv * c + iv * gv;
            hcur = ov * tanhf_fast(c);
            hs[j] = (_Float16)hcur;
            if (WRITE_Y) Yout[((size_t)b * T + t) * 128 + j] = (_Float16)hcur;
        }
        __syncthreads();                              // new h visible for next step
        xp = xpn;
    }
    if (g < 128) {
        fh[(size_t)b * 128 + g] = hcur;
        fc[(size_t)b * 128 + g] = c;
    }
}

// ---------------------------------------------------------------------------
// Host side: 8 stream-ordered launches.
//   ws layout: XP f16 [131072,512] (128MB) | Y f16 [131072,128] (32MB)
//              | fh0,fc0,fh1,fc1 f32 [64,128] each
// ---------------------------------------------------------------------------
extern "C" void kernel_launch(void* const* d_in, const int* in_sizes, int n_in,
                              void* d_out, int out_size, void* d_ws, size_t ws_size,
                              hipStream_t stream)
{
    const float* x    = (const float*)d_in[0];
    const float* eW0  = (const float*)d_in[1];
    const float* eU0  = (const float*)d_in[2];
    const float* eb0i = (const float*)d_in[3];
    const float* eb0h = (const float*)d_in[4];
    const float* eW1  = (const float*)d_in[5];
    const float* eU1  = (const float*)d_in[6];
    const float* eb1i = (const float*)d_in[7];
    const float* eb1h = (const float*)d_in[8];
    const float* dW0  = (const float*)d_in[9];   (void)dW0;  // dec L0 input is zeros
    const float* dU0  = (const float*)d_in[10];
    const float* db0i = (const float*)d_in[11];
    const float* db0h = (const float*)d_in[12];
    const float* dW1  = (const float*)d_in[13];
    const float* dU1  = (const float*)d_in[14];
    const float* db1i = (const float*)d_in[15];
    const float* db1h = (const float*)d_in[16];
    const float* oW   = (const float*)d_in[17];
    const float* ob   = (const float*)d_in[18];

    char* ws = (char*)d_ws;
    _Float16* XP = (_Float16*)ws;                               // 134217728 B
    _Float16* Y  = (_Float16*)(ws + 134217728);                 //  33554432 B
    float*    fh0 = (float*)(ws + 167772160);
    float*    fc0 = fh0 + Bsz * Hd;
    float*    fh1 = fc0 + Bsz * Hd;
    float*    fc1 = fh1 + Bsz * Hd;

    dim3 blk(256);
    dim3 g512(Mrows / 64, G4 / 64);   // 2048 x 8
    dim3 g128(Mrows / 64, Hd / 64);   // 2048 x 2
    dim3 rgrid(Bsz);
    dim3 rblk(512);

    // 1) XP = x @ enc_Wih0^T
    gemm_k128<false, false><<<g512, blk, 0, stream>>>((const void*)x, eW0, (const float*)nullptr, (void*)XP, Mrows, G4);
    // 2) enc L0: XP -> Y(y0), finals fh0/fc0
    lstm_rec<true, true, false><<<rgrid, rblk, 0, stream>>>(
        eU0, eb0i, eb0h, XP, (const float*)nullptr, (const float*)nullptr, Y, fh0, fc0, Tlen);
    // 3) XP = y0 @ enc_Wih1^T
    gemm_k128<true, false><<<g512, blk, 0, stream>>>((const void*)Y, eW1, (const float*)nullptr, (void*)XP, Mrows, G4);
    // 4) enc L1: XP -> finals fh1/fc1 (y1 discarded)
    lstm_rec<true, false, false><<<rgrid, rblk, 0, stream>>>(
        eU1, eb1i, eb1h, XP, (const float*)nullptr, (const float*)nullptr, (_Float16*)nullptr, fh1, fc1, Tlen);
    // 5) dec L0: zeros input -> no XP; init (fh0,fc0); writes Y(d0)
    lstm_rec<false, true, true><<<rgrid, rblk, 0, stream>>>(
        dU0, db0i, db0h, (const _Float16*)nullptr, fh0, fc0, Y, fh0, fc0, Tlen);
    // 6) XP = d0 @ dec_Wih1^T
    gemm_k128<true, false><<<g512, blk, 0, stream>>>((const void*)Y, dW1, (const float*)nullptr, (void*)XP, Mrows, G4);
    // 7) dec L1: XP; init (fh1,fc1); writes Y(d1)
    lstm_rec<true, true, true><<<rgrid, rblk, 0, stream>>>(
        dU1, db1i, db1h, XP, fh1, fc1, Y, fh1, fc1, Tlen);
    // 8) out = d1 @ out_W^T + out_b  (f32 -> d_out)
    gemm_k128<true, true><<<g128, blk, 0, stream>>>((const void*)Y, oW, ob, d_out, Mrows, Hd);
}